// Round 3
// baseline (8235.322 us; speedup 1.0000x reference)
//
#include <hip/hip_runtime.h>
#include <hip/hip_bf16.h>
#include <math.h>

#define B_ 32
#define T_ 64
#define S_ 128
#define V_ 32000
#define E_ 256
#define U_ 1024

typedef __bf16 bf16_t;
typedef __bf16 bf16x8 __attribute__((ext_vector_type(8)));
typedef float f32x4 __attribute__((ext_vector_type(4)));

__device__ __forceinline__ float sigm(float x) { return 1.f / (1.f + expf(-x)); }

__device__ __forceinline__ bf16x8 cvt8(const float* p) {
    float4 f0 = *(const float4*)p;
    float4 f1 = *(const float4*)(p + 4);
    bf16x8 v;
    v[0] = (bf16_t)f0.x; v[1] = (bf16_t)f0.y; v[2] = (bf16_t)f0.z; v[3] = (bf16_t)f0.w;
    v[4] = (bf16_t)f1.x; v[5] = (bf16_t)f1.y; v[6] = (bf16_t)f1.z; v[7] = (bf16_t)f1.w;
    return v;
}

// ---------------- fp32 -> bf16 bulk convert (n divisible by 2048) ----------------
__global__ void k_cvt(const float* __restrict__ src, bf16_t* __restrict__ dst) {
    int i = (blockIdx.x * 256 + threadIdx.x) * 8;
    *(bf16x8*)(dst + i) = cvt8(src + i);
}

// ---------------- init: h,c from h0,c0 (fp32 in) ----------------
__global__ void k_init(const float* h0, const float* c0, bf16_t* h_bf, float* c_f) {
    int i = blockIdx.x * 256 + threadIdx.x;   // 32*1024 = 32768 total
    h_bf[i] = (bf16_t)h0[i];
    c_f[i] = c0[i];
}

// ---------------- embed: x_all[t][b][e] = emb[tokens[b][t]][e] (fp32 -> bf16) ----------------
__global__ void k_embed(const int* tokens, const float* emb, bf16_t* x_all) {
    int i = blockIdx.x * 256 + threadIdx.x;   // T*B*E = 524288
    int e = i & (E_ - 1);
    int b = (i >> 8) & 31;
    int t = i >> 13;
    int tok = tokens[b * T_ + t];
    x_all[(t * B_ + b) * E_ + e] = (bf16_t)emb[tok * E_ + e];
}

// ---------------- big GEMM ----------------
// MODE 0: A fp32 (enc), B fp32 (W2), out fp32 keys[row*N+col]
// MODE 1: A bf16 (h_all), B fp32 (Wf), out fp32 logits remapped [B,T,V]
template <int MODE>
__global__ __launch_bounds__(256) void k_gemm_big(const void* __restrict__ Av,
                                                  const float* __restrict__ Bm,
                                                  const float* __restrict__ bias,
                                                  float* __restrict__ outf,
                                                  int M, int N, int K) {
    __shared__ bf16_t As[128 * 64];
    __shared__ bf16_t Bs[64 * 128];
    const int tid = threadIdx.x;
    const int wave = tid >> 6, lane = tid & 63;
    const int quad = lane >> 4, l16 = lane & 15;
    const int m0 = blockIdx.x * 128, n0 = blockIdx.y * 128;
    const int wm = (wave >> 1) * 64, wn = (wave & 1) * 64;
    f32x4 acc[4][4] = {};
    for (int k0 = 0; k0 < K; k0 += 64) {
        __syncthreads();
        {
            for (int it = 0; it < 4; ++it) {
                int idx = it * 256 + tid;            // 1024 chunks of 8 elems
                int r = idx >> 3, c = (idx & 7) * 8; // A tile 128 x 64
                if (MODE == 0) {
                    const float* Ag = (const float*)Av + (long)m0 * K + k0;
                    *(bf16x8*)&As[r * 64 + c] = cvt8(Ag + (long)r * K + c);
                } else {
                    const bf16_t* Ag = (const bf16_t*)Av + (long)m0 * K + k0;
                    *(bf16x8*)&As[r * 64 + c] = *(const bf16x8*)(Ag + (long)r * K + c);
                }
            }
            const float* Bg = Bm + (long)k0 * N + n0;
            for (int it = 0; it < 4; ++it) {
                int idx = it * 256 + tid;             // 1024 chunks
                int r = idx >> 4, c = (idx & 15) * 8; // B tile 64 x 128
                *(bf16x8*)&Bs[r * 128 + c] = cvt8(Bg + (long)r * N + c);
            }
        }
        __syncthreads();
        for (int s = 0; s < 2; ++s) {
            bf16x8 af[4];
            for (int mt = 0; mt < 4; ++mt)
                af[mt] = *(const bf16x8*)&As[(wm + mt * 16 + l16) * 64 + s * 32 + quad * 8];
            for (int nt = 0; nt < 4; ++nt) {
                bf16x8 bfr;
                int col = wn + nt * 16 + l16;
                for (int j = 0; j < 8; ++j)
                    bfr[j] = Bs[(s * 32 + quad * 8 + j) * 128 + col];
                for (int mt = 0; mt < 4; ++mt)
                    acc[mt][nt] = __builtin_amdgcn_mfma_f32_16x16x32_bf16(af[mt], bfr, acc[mt][nt], 0, 0, 0);
            }
        }
    }
    for (int mt = 0; mt < 4; ++mt)
        for (int nt = 0; nt < 4; ++nt)
            for (int r = 0; r < 4; ++r) {
                int row = m0 + wm + mt * 16 + quad * 4 + r;
                int col = n0 + wn + nt * 16 + l16;
                float v = acc[mt][nt][r] + bias[col];
                if (MODE == 0) {
                    outf[(long)row * N + col] = v;
                } else {
                    int t = row >> 5, b = row & 31;
                    outf[((long)(b * T_ + t)) * V_ + col] = v;
                }
            }
}

// ---------------- per-step skinny GEMM: q = h@W1+b1 ; zpart = h@Wr + x_t@Wk[0:256] + bl ----
__global__ __launch_bounds__(256) void k_qz(const bf16_t* __restrict__ h_bf,
                                            const bf16_t* __restrict__ x_t,
                                            const bf16_t* __restrict__ W1b,
                                            const float* __restrict__ b1,
                                            const bf16_t* __restrict__ Wrb,
                                            const bf16_t* __restrict__ Wkb,
                                            const float* __restrict__ bl,
                                            float* __restrict__ q, float* __restrict__ zpart) {
    __shared__ bf16_t As[32 * 64];
    __shared__ bf16_t Bs[64 * 64];
    const int tid = threadIdx.x, wave = tid >> 6, lane = tid & 63;
    const int quad = lane >> 4, l16 = lane & 15;
    const bool isQ = blockIdx.x < 16;
    const int n0 = isQ ? blockIdx.x * 64 : (blockIdx.x - 16) * 64;
    const int K = isQ ? 1024 : 1280;
    f32x4 acc[2] = {};
    for (int k0 = 0; k0 < K; k0 += 64) {
        __syncthreads();
        {
            int r = tid >> 3, c = (tid & 7) * 8;   // 32 rows x 8 chunks
            const bf16_t* src = (k0 < 1024) ? (h_bf + r * 1024 + k0 + c)
                                            : (x_t + r * 256 + (k0 - 1024) + c);
            *(bf16x8*)&As[r * 64 + c] = *(const bf16x8*)src;
        }
        for (int it = 0; it < 2; ++it) {
            int idx = it * 256 + tid;
            int r = idx >> 3, c = (idx & 7) * 8;   // 64 rows x 8 chunks
            const bf16_t* src;
            if (isQ)            src = W1b + (k0 + r) * 1024 + n0 + c;
            else if (k0 < 1024) src = Wrb + (k0 + r) * 4096 + n0 + c;
            else                src = Wkb + (k0 - 1024 + r) * 4096 + n0 + c;
            *(bf16x8*)&Bs[r * 64 + c] = *(const bf16x8*)src;
        }
        __syncthreads();
        for (int s = 0; s < 2; ++s) {
            bf16x8 af[2];
            for (int mt = 0; mt < 2; ++mt)
                af[mt] = *(const bf16x8*)&As[(mt * 16 + l16) * 64 + s * 32 + quad * 8];
            bf16x8 bfr;
            int col = wave * 16 + l16;
            for (int j = 0; j < 8; ++j)
                bfr[j] = Bs[(s * 32 + quad * 8 + j) * 64 + col];
            for (int mt = 0; mt < 2; ++mt)
                acc[mt] = __builtin_amdgcn_mfma_f32_16x16x32_bf16(af[mt], bfr, acc[mt], 0, 0, 0);
        }
    }
    for (int mt = 0; mt < 2; ++mt)
        for (int r = 0; r < 4; ++r) {
            int row = mt * 16 + quad * 4 + r;
            int col = n0 + wave * 16 + l16;
            if (isQ) q[row * 1024 + col] = acc[mt][r] + b1[col];
            else     zpart[row * 4096 + col] = acc[mt][r] + bl[col];
        }
}

// ---------------- scores[b][s] = Va . tanh(q[b] + keys[b][s]) + bv ----------------
__global__ __launch_bounds__(256) void k_score(const float* __restrict__ q,
                                               const float* __restrict__ keys,
                                               const float* __restrict__ Va,
                                               const float* __restrict__ bv,
                                               float* __restrict__ scores) {
    __shared__ float qs[1024];
    __shared__ float va[1024];
    const int b = blockIdx.x, sc = blockIdx.y;
    const int tid = threadIdx.x, wave = tid >> 6, lane = tid & 63;
    for (int i = tid; i < 1024; i += 256) {
        qs[i] = q[b * 1024 + i];
        va[i] = Va[i];
    }
    __syncthreads();
    float bvf = bv[0];
    for (int i = 0; i < 8; ++i) {
        int s = sc * 32 + i * 4 + wave;
        const float* kp = keys + (b * 128 + s) * 1024;
        float p = 0.f;
        for (int u = lane; u < 1024; u += 64)
            p += tanhf(qs[u] + kp[u]) * va[u];
        for (int off = 32; off; off >>= 1) p += __shfl_down(p, off);
        if (lane == 0) scores[b * 128 + s] = p + bvf;
    }
}

// ---------------- ctx[b][u] = softmax(scores[b]) . enc[b][:,u] ----------------
__global__ __launch_bounds__(256) void k_ctx(const float* __restrict__ scores,
                                             const float* __restrict__ enc,
                                             bf16_t* __restrict__ ctx) {
    __shared__ float w[128];
    const int b = blockIdx.x, uc = blockIdx.y, tid = threadIdx.x;
    if (tid < 64) {
        float s0 = scores[b * 128 + tid], s1 = scores[b * 128 + 64 + tid];
        float m = fmaxf(s0, s1);
        for (int off = 32; off; off >>= 1) m = fmaxf(m, __shfl_down(m, off));
        m = __shfl(m, 0);
        float e0 = expf(s0 - m), e1 = expf(s1 - m);
        float sum = e0 + e1;
        for (int off = 32; off; off >>= 1) sum += __shfl_down(sum, off);
        sum = __shfl(sum, 0);
        w[tid] = e0 / sum;
        w[tid + 64] = e1 / sum;
    }
    __syncthreads();
    int u = uc * 256 + tid;
    const float* ep = enc + b * (128 * 1024) + u;
    float a = 0.f;
    for (int s = 0; s < 128; ++s) a += w[s] * ep[s * 1024];
    ctx[b * 1024 + u] = (bf16_t)a;
}

// ---------------- zfinal = ctx@Wk[256:1280] + zpart ; gates ; h,c update ----------------
__global__ __launch_bounds__(256) void k_zg(const bf16_t* __restrict__ ctx,
                                            const bf16_t* __restrict__ Wkb,
                                            const float* __restrict__ zpart,
                                            float* __restrict__ c_f,
                                            bf16_t* __restrict__ h_bf,
                                            bf16_t* __restrict__ h_all_t) {
    __shared__ bf16_t As[32 * 64];
    __shared__ bf16_t Bs[4 * 64 * 16];   // [gate][k][16]
    __shared__ float zle[4 * 32 * 16];   // [gate][b][16]
    const int tid = threadIdx.x, wave = tid >> 6, lane = tid & 63;
    const int quad = lane >> 4, l16 = lane & 15;
    const int u0 = blockIdx.x * 16;
    f32x4 acc[2] = {};
    for (int k0 = 0; k0 < 1024; k0 += 64) {
        __syncthreads();
        {
            int r = tid >> 3, c = (tid & 7) * 8;
            *(bf16x8*)&As[r * 64 + c] = *(const bf16x8*)(ctx + r * 1024 + k0 + c);
        }
        for (int it = 0; it < 2; ++it) {
            int idx = it * 256 + tid;           // chunk id over 4096 elems
            int g = idx >> 7;                   // 128 chunks per gate strip
            int rem = idx & 127;
            int r = rem >> 1, c = (rem & 1) * 8;
            *(bf16x8*)&Bs[g * 1024 + r * 16 + c] =
                *(const bf16x8*)(Wkb + (256 + k0 + r) * 4096 + g * 1024 + u0 + c);
        }
        __syncthreads();
        for (int s = 0; s < 2; ++s) {
            bf16x8 af[2];
            for (int mt = 0; mt < 2; ++mt)
                af[mt] = *(const bf16x8*)&As[(mt * 16 + l16) * 64 + s * 32 + quad * 8];
            bf16x8 bfr;
            for (int j = 0; j < 8; ++j)
                bfr[j] = Bs[wave * 1024 + (s * 32 + quad * 8 + j) * 16 + l16];
            for (int mt = 0; mt < 2; ++mt)
                acc[mt] = __builtin_amdgcn_mfma_f32_16x16x32_bf16(af[mt], bfr, acc[mt], 0, 0, 0);
        }
    }
    for (int mt = 0; mt < 2; ++mt)
        for (int r = 0; r < 4; ++r) {
            int row = mt * 16 + quad * 4 + r;
            zle[wave * 512 + row * 16 + l16] = acc[mt][r];
        }
    __syncthreads();
    for (int rep = 0; rep < 2; ++rep) {
        int oi = rep * 256 + tid;   // 512 outputs (b,u)
        int b = oi >> 4, u = oi & 15;
        int ug = u0 + u;
        float zi = zle[0 * 512 + b * 16 + u] + zpart[b * 4096 + 0 * 1024 + ug];
        float zf = zle[1 * 512 + b * 16 + u] + zpart[b * 4096 + 1 * 1024 + ug];
        float zg = zle[2 * 512 + b * 16 + u] + zpart[b * 4096 + 2 * 1024 + ug];
        float zo = zle[3 * 512 + b * 16 + u] + zpart[b * 4096 + 3 * 1024 + ug];
        float cn = sigm(zf) * c_f[b * 1024 + ug] + sigm(zi) * tanhf(zg);
        float hn = sigm(zo) * tanhf(cn);
        c_f[b * 1024 + ug] = cn;
        bf16_t hb = (bf16_t)hn;
        h_bf[b * 1024 + ug] = hb;
        h_all_t[b * 1024 + ug] = hb;
    }
}

extern "C" void kernel_launch(void* const* d_in, const int* in_sizes, int n_in,
                              void* d_out, int out_size, void* d_ws, size_t ws_size,
                              hipStream_t stream) {
    const int*   tokens = (const int*)d_in[0];
    const float* h0     = (const float*)d_in[1];
    const float* c0     = (const float*)d_in[2];
    const float* enc    = (const float*)d_in[3];
    const float* emb    = (const float*)d_in[4];
    const float* W1     = (const float*)d_in[5];
    const float* b1     = (const float*)d_in[6];
    const float* W2     = (const float*)d_in[7];
    const float* b2     = (const float*)d_in[8];
    const float* Va     = (const float*)d_in[9];
    const float* bv     = (const float*)d_in[10];
    const float* Wk     = (const float*)d_in[11];
    const float* Wr     = (const float*)d_in[12];
    const float* bl     = (const float*)d_in[13];
    const float* Wf     = (const float*)d_in[14];
    const float* bfv    = (const float*)d_in[15];

    char* ws = (char*)d_ws;
    float* keys   = (float*)ws; ws += 32 * 128 * 1024 * 4;   // 16.8 MB
    float* q      = (float*)ws; ws += 32 * 1024 * 4;
    float* zpart  = (float*)ws; ws += 32 * 4096 * 4;
    float* scores = (float*)ws; ws += 32 * 128 * 4;
    float* c_f    = (float*)ws; ws += 32 * 1024 * 4;
    bf16_t* ctx   = (bf16_t*)ws; ws += 32 * 1024 * 2;
    bf16_t* h_bf  = (bf16_t*)ws; ws += 32 * 1024 * 2;
    bf16_t* x_all = (bf16_t*)ws; ws += 64 * 32 * 256 * 2;
    bf16_t* h_all = (bf16_t*)ws; ws += 64 * 32 * 1024 * 2;
    bf16_t* W1b   = (bf16_t*)ws; ws += 1024 * 1024 * 2;
    bf16_t* Wrb   = (bf16_t*)ws; ws += 1024 * 4096 * 2;
    bf16_t* Wkb   = (bf16_t*)ws; ws += 1280 * 4096 * 2;
    float* out    = (float*)d_out;

    k_init<<<128, 256, 0, stream>>>(h0, c0, h_bf, c_f);
    k_embed<<<2048, 256, 0, stream>>>(tokens, emb, x_all);
    k_cvt<<<512, 256, 0, stream>>>(W1, W1b);    // 1024*1024
    k_cvt<<<2048, 256, 0, stream>>>(Wr, Wrb);   // 1024*4096
    k_cvt<<<2560, 256, 0, stream>>>(Wk, Wkb);   // 1280*4096
    // keys = enc @ W2 + b2  (M=4096, N=1024, K=1024), fp32 out
    k_gemm_big<0><<<dim3(32, 8), 256, 0, stream>>>(enc, W2, b2, keys, 4096, 1024, 1024);

    for (int t = 0; t < T_; ++t) {
        k_qz<<<80, 256, 0, stream>>>(h_bf, x_all + t * B_ * E_, W1b, b1, Wrb, Wkb, bl, q, zpart);
        k_score<<<dim3(32, 4), 256, 0, stream>>>(q, keys, Va, bv, scores);
        k_ctx<<<dim3(32, 4), 256, 0, stream>>>(scores, enc, ctx);
        k_zg<<<64, 256, 0, stream>>>(ctx, Wkb, zpart, c_f, h_bf, h_all + t * B_ * U_);
    }
    // logits = h_all @ Wf + bf  (M=2048, N=32000, K=1024), fp32 out remapped to [B,T,V]
    k_gemm_big<1><<<dim3(16, 250), 256, 0, stream>>>(h_all, Wf, bfv, out, 2048, 32000, 1024);
}